// Round 5
// baseline (1502.009 us; speedup 1.0000x reference)
//
#include <hip/hip_runtime.h>
#include <hip/hip_bf16.h>
#include <math.h>

#define CDIM 1024
#define LDIM 2048
#define NROWS 8192      // B*L
#define ATTROWS 1152    // rows of q/k/v consumed per batch (windows 0..7)

typedef __bf16 bf16x8 __attribute__((ext_vector_type(8)));
typedef __bf16 bf16x4 __attribute__((ext_vector_type(4)));
typedef float f32x4 __attribute__((ext_vector_type(4)));

__device__ __forceinline__ float gelu_exact(float v) {
  return 0.5f * v * (1.0f + erff(v * 0.70710678118654752440f));
}

__device__ __forceinline__ void gload_lds(const __bf16* g, __bf16* l) {
  __builtin_amdgcn_global_load_lds(
      (const __attribute__((address_space(1))) void*)(const void*)g,
      (__attribute__((address_space(3))) void*)(void*)l, 16, 0, 0);
}

// ---------------- fp32 -> (hi,lo) bf16 split, vectorized ----------------
__global__ __launch_bounds__(256) void split_pair(const float* __restrict__ src,
                                                  __bf16* __restrict__ hi,
                                                  __bf16* __restrict__ lo,
                                                  int n4) {
  int idx = blockIdx.x * 256 + threadIdx.x;
  int stride = gridDim.x * 256;
  for (int i = idx; i < n4; i += stride) {
    float4 v = ((const float4*)src)[i];
    bf16x4 h, l;
    h[0] = (__bf16)v.x; l[0] = (__bf16)(v.x - (float)h[0]);
    h[1] = (__bf16)v.y; l[1] = (__bf16)(v.y - (float)h[1]);
    h[2] = (__bf16)v.z; l[2] = (__bf16)(v.z - (float)h[2]);
    h[3] = (__bf16)v.w; l[3] = (__bf16)(v.w - (float)h[3]);
    ((bf16x4*)hi)[i] = h;
    ((bf16x4*)lo)[i] = l;
  }
}

// ---------------- conv weight transpose+split: w2[o][k*1024+i] = cw[o][i][k]
__global__ __launch_bounds__(256) void convw_split(const float* __restrict__ cw,
                                                   __bf16* __restrict__ wh,
                                                   __bf16* __restrict__ wl) {
  int idx = blockIdx.x * 256 + threadIdx.x;  // < 1024*3072
  int o = idx / 3072;
  int r = idx - o * 3072;
  int k = r >> 10;
  int i = r & 1023;
  float v = cw[(size_t)(o * 1024 + i) * 3 + k];
  __bf16 h = (__bf16)v;
  wh[idx] = h;
  wl[idx] = (__bf16)(v - (float)h);
}

// ---------------- zero pads of the ln2 padded buffer (rows 0,1,2050,2051) ---
__global__ __launch_bounds__(256) void zero_pads(__bf16* __restrict__ ph,
                                                 __bf16* __restrict__ pl) {
  int i = blockIdx.x * 256 + threadIdx.x;  // < 16384
  if (i >= 16384) return;
  int b = i >> 12;
  int r4 = (i >> 10) & 3;
  int c = i & 1023;
  int row = b * 2052 + (r4 < 2 ? r4 : 2048 + r4);
  ph[(size_t)row * 1024 + c] = (__bf16)0.f;
  pl[(size_t)row * 1024 + c] = (__bf16)0.f;
}

// ---------------- LayerNorm -> (hi,lo) bf16 pair planes ----------------
__global__ __launch_bounds__(256) void ln_pair(
    const float* __restrict__ src, __bf16* __restrict__ dh,
    __bf16* __restrict__ dl, const float* __restrict__ g,
    const float* __restrict__ b, int rows_pb, int src_bstride, int dst_bstride,
    int dst_pad) {
  int r = blockIdx.x;
  int bb = r / rows_pb, l = r - bb * rows_pb;
  const float4* row =
      (const float4*)(src + (size_t)(bb * src_bstride + l) * CDIM);
  size_t drow = (size_t)(bb * dst_bstride + dst_pad + l) * CDIM;
  int t = threadIdx.x;
  float4 v = row[t];
  float s = v.x + v.y + v.z + v.w;
  float sq = v.x * v.x + v.y * v.y + v.z * v.z + v.w * v.w;
#pragma unroll
  for (int off = 32; off > 0; off >>= 1) {
    s += __shfl_down(s, off);
    sq += __shfl_down(sq, off);
  }
  __shared__ float red[8];
  int wave = t >> 6;
  if ((t & 63) == 0) {
    red[wave] = s;
    red[4 + wave] = sq;
  }
  __syncthreads();
  if (t == 0) {
    float st = red[0] + red[1] + red[2] + red[3];
    float sqt = red[4] + red[5] + red[6] + red[7];
    float m = st * (1.0f / CDIM);
    float var = sqt * (1.0f / CDIM) - m * m;
    red[0] = m;
    red[1] = rsqrtf(var + 1e-5f);
  }
  __syncthreads();
  float m = red[0], rs = red[1];
  float4 gv = ((const float4*)g)[t];
  float4 bv = ((const float4*)b)[t];
  float o0 = (v.x - m) * rs * gv.x + bv.x;
  float o1 = (v.y - m) * rs * gv.y + bv.y;
  float o2 = (v.z - m) * rs * gv.z + bv.z;
  float o3 = (v.w - m) * rs * gv.w + bv.w;
  bf16x4 h, lo4;
  h[0] = (__bf16)o0; lo4[0] = (__bf16)(o0 - (float)h[0]);
  h[1] = (__bf16)o1; lo4[1] = (__bf16)(o1 - (float)h[1]);
  h[2] = (__bf16)o2; lo4[2] = (__bf16)(o2 - (float)h[2]);
  h[3] = (__bf16)o3; lo4[3] = (__bf16)(o3 - (float)h[3]);
  *(bf16x4*)&dh[drow + t * 4] = h;
  *(bf16x4*)&dl[drow + t * 4] = lo4;
}

// ---------------- LayerNorm + fused MoE gate (ln3): also emits gp_t[8][N] --
__global__ __launch_bounds__(256) void ln_pair_gate(
    const float* __restrict__ src, __bf16* __restrict__ dh,
    __bf16* __restrict__ dl, const float* __restrict__ g,
    const float* __restrict__ b, const float* __restrict__ gw,
    const float* __restrict__ gb, float* __restrict__ gpt) {
  int r = blockIdx.x;
  const float4* row = (const float4*)(src + (size_t)r * CDIM);
  size_t drow = (size_t)r * CDIM;
  int t = threadIdx.x;
  float4 v = row[t];
  float s = v.x + v.y + v.z + v.w;
  float sq = v.x * v.x + v.y * v.y + v.z * v.z + v.w * v.w;
#pragma unroll
  for (int off = 32; off > 0; off >>= 1) {
    s += __shfl_down(s, off);
    sq += __shfl_down(sq, off);
  }
  __shared__ float red[8];
  __shared__ float gred[4][8];
  int wave = t >> 6;
  if ((t & 63) == 0) {
    red[wave] = s;
    red[4 + wave] = sq;
  }
  __syncthreads();
  if (t == 0) {
    float st = red[0] + red[1] + red[2] + red[3];
    float sqt = red[4] + red[5] + red[6] + red[7];
    float m = st * (1.0f / CDIM);
    float var = sqt * (1.0f / CDIM) - m * m;
    red[0] = m;
    red[1] = rsqrtf(var + 1e-5f);
  }
  __syncthreads();
  float m = red[0], rs = red[1];
  float4 gv = ((const float4*)g)[t];
  float4 bv = ((const float4*)b)[t];
  float o0 = (v.x - m) * rs * gv.x + bv.x;
  float o1 = (v.y - m) * rs * gv.y + bv.y;
  float o2 = (v.z - m) * rs * gv.z + bv.z;
  float o3 = (v.w - m) * rs * gv.w + bv.w;
  bf16x4 h, lo4;
  h[0] = (__bf16)o0; lo4[0] = (__bf16)(o0 - (float)h[0]);
  h[1] = (__bf16)o1; lo4[1] = (__bf16)(o1 - (float)h[1]);
  h[2] = (__bf16)o2; lo4[2] = (__bf16)(o2 - (float)h[2]);
  h[3] = (__bf16)o3; lo4[3] = (__bf16)(o3 - (float)h[3]);
  *(bf16x4*)&dh[drow + t * 4] = h;
  *(bf16x4*)&dl[drow + t * 4] = lo4;
  // gate partial dots on the fp32 LN output held in registers
  float gp8[8];
#pragma unroll
  for (int e = 0; e < 8; e++) {
    float4 w = ((const float4*)gw)[e * 256 + t];
    gp8[e] = o0 * w.x + o1 * w.y + o2 * w.z + o3 * w.w;
  }
#pragma unroll
  for (int off = 32; off > 0; off >>= 1)
#pragma unroll
    for (int e = 0; e < 8; e++) gp8[e] += __shfl_down(gp8[e], off);
  if ((t & 63) == 0)
#pragma unroll
    for (int e = 0; e < 8; e++) gred[wave][e] = gp8[e];
  __syncthreads();
  if (t == 0) {
    float lg[8];
#pragma unroll
    for (int e = 0; e < 8; e++)
      lg[e] = gred[0][e] + gred[1][e] + gred[2][e] + gred[3][e] + gb[e];
    float mx = lg[0];
#pragma unroll
    for (int e = 1; e < 8; e++) mx = fmaxf(mx, lg[e]);
    float ex[8];
    float sum = 0.f;
#pragma unroll
    for (int e = 0; e < 8; e++) {
      ex[e] = expf(lg[e] - mx);
      sum += ex[e];
    }
    float inv = 1.0f / sum;
#pragma unroll
    for (int e = 0; e < 8; e++) gpt[(size_t)e * NROWS + r] = ex[e] * inv;
  }
}

// ---------------- fused local attention (unfold-faithful), bf16 in/out ------
__global__ __launch_bounds__(256) void attn_kernel(const __bf16* __restrict__ QKV,
                                                   __bf16* __restrict__ Oh,
                                                   __bf16* __restrict__ Ol) {
  __shared__ float Qc[64][68];
  __shared__ float Kc[64][68];
  __shared__ float At[64][65];
  int blk = blockIdx.x;
  int n = blk & 7, hd_ = (blk >> 3) & 15, b = blk >> 7;
  int t = threadIdx.x;
  int dt = t >> 4, et = t & 15;
  int lw = t >> 4, lf = (t & 15) * 4;
  const __bf16* base = QKV + (size_t)(b * ATTROWS + n * 128) * 3072 + hd_ * 64;
  float acc[4][4] = {};
  for (int wcc = 0; wcc < 4; wcc++) {
    __syncthreads();
#pragma unroll
    for (int p = 0; p < 4; p++) {
      int w = p * 16 + lw;
      const __bf16* rp = base + (size_t)(wcc * 64 + w) * 3072 + lf;
      bf16x4 qv = *(const bf16x4*)rp;
      bf16x4 kv = *(const bf16x4*)(rp + 1024);
      Qc[w][lf + 0] = (float)qv[0]; Qc[w][lf + 1] = (float)qv[1];
      Qc[w][lf + 2] = (float)qv[2]; Qc[w][lf + 3] = (float)qv[3];
      Kc[w][lf + 0] = (float)kv[0]; Kc[w][lf + 1] = (float)kv[1];
      Kc[w][lf + 2] = (float)kv[2]; Kc[w][lf + 3] = (float)kv[3];
    }
    __syncthreads();
#pragma unroll 8
    for (int k = 0; k < 64; k++) {
      float4 qa = *(const float4*)&Qc[k][dt * 4];
      float4 kb = *(const float4*)&Kc[k][et * 4];
      float a4[4] = {qa.x, qa.y, qa.z, qa.w};
      float b4[4] = {kb.x, kb.y, kb.z, kb.w};
#pragma unroll
      for (int i = 0; i < 4; i++)
#pragma unroll
        for (int j = 0; j < 4; j++) acc[i][j] = fmaf(a4[i], b4[j], acc[i][j]);
    }
  }
  __syncthreads();
#pragma unroll
  for (int i = 0; i < 4; i++)
#pragma unroll
    for (int j = 0; j < 4; j++) At[dt * 4 + i][et * 4 + j] = acc[i][j] * 0.125f;
  __syncthreads();
  if (t < 64) {  // softmax over e per row d=t
    float mx = -1e30f;
    for (int e = 0; e < 64; e++) mx = fmaxf(mx, At[t][e]);
    float s = 0.f;
    for (int e = 0; e < 64; e++) {
      float ex = expf(At[t][e] - mx);
      At[t][e] = ex;
      s += ex;
    }
    float inv = 1.0f / s;
    for (int e = 0; e < 64; e++) At[t][e] *= inv;
  }
  __syncthreads();
  float* Vc = &Qc[0][0];  // reuse Qc as Vc[e][j], stride 68
  for (int wb = 0; wb < 4; wb++) {
    __syncthreads();
#pragma unroll
    for (int p = 0; p < 4; p++) {
      int j = p * 16 + lw;
      const __bf16* rp = base + (size_t)(wb * 64 + j) * 3072 + 2048 + lf;
      bf16x4 vv = *(const bf16x4*)rp;
      Vc[(lf + 0) * 68 + j] = (float)vv[0];
      Vc[(lf + 1) * 68 + j] = (float)vv[1];
      Vc[(lf + 2) * 68 + j] = (float)vv[2];
      Vc[(lf + 3) * 68 + j] = (float)vv[3];
    }
    __syncthreads();
    float o[4][4] = {};
    for (int e = 0; e < 64; e++) {
      float a4[4] = {At[dt * 4 + 0][e], At[dt * 4 + 1][e], At[dt * 4 + 2][e],
                     At[dt * 4 + 3][e]};
      float4 vv = *(const float4*)&Vc[e * 68 + et * 4];
      float b4[4] = {vv.x, vv.y, vv.z, vv.w};
#pragma unroll
      for (int i = 0; i < 4; i++)
#pragma unroll
        for (int j = 0; j < 4; j++) o[i][j] = fmaf(a4[i], b4[j], o[i][j]);
    }
#pragma unroll
    for (int i = 0; i < 4; i++) {
      int d = dt * 4 + i;
      int tok = n * 256 + d * 4 + wb;
      size_t ob = (size_t)(b * LDIM + tok) * CDIM + hd_ * 64 + et * 4;
      bf16x4 oh, ol;
#pragma unroll
      for (int jj = 0; jj < 4; jj++) {
        float v = o[i][jj];
        __bf16 hh = (__bf16)v;
        oh[jj] = hh;
        ol[jj] = (__bf16)(v - (float)hh);
      }
      *(bf16x4*)&Oh[ob] = oh;
      *(bf16x4*)&Ol[ob] = ol;
    }
  }
}

// ---------------- split-bf16 MFMA GEMM: C = A@B^T (+bias, epilogues) -------
// 128x128 tile, BK=64, 4 waves (2x2), 4x4 frags of 16x16x32 per wave.
// A,B stored [rows][K] as bf16 hi/lo planes. XOR-swizzled LDS (byte^(row&7)<<4).
// EP: 0 = bf16 single out (bias), 1 = fp32 out = acc+bias+res,
//     2 = bf16 single out gelu(acc+bias).
template <int EP, bool APAIR, bool CONV>
__global__ __launch_bounds__(256) void mgemm(
    const __bf16* __restrict__ Ah, const __bf16* __restrict__ Al,
    const __bf16* __restrict__ Bh, const __bf16* __restrict__ Bl,
    const float* __restrict__ bias, const float* __restrict__ res,
    float* __restrict__ Cf, __bf16* __restrict__ Cb, int Nc, int K, int a_off,
    int c_off) {
  __shared__ __bf16 sAh[8192];
  __shared__ __bf16 sAl[8192];
  __shared__ __bf16 sBh[8192];
  __shared__ __bf16 sBl[8192];
  int t = threadIdx.x;
  int wv = t >> 6, ln = t & 63;
  int wr = wv >> 1, wc = wv & 1;
  int n0 = blockIdx.x * 128, m0 = blockIdx.y * 128;
  int srow = ln >> 3;
  int kel = ((ln & 7) ^ srow) << 3;      // swizzled source k-elem offset
  int dst = wv * 512 + ln * 8;           // LDS elems (per q: +q*2048)
  int lr = ln & 15, lg = ln >> 4;
  int swz = (ln & 7) << 4;
  int kb = lg << 4;
  f32x4 acc[4][4];
#pragma unroll
  for (int i = 0; i < 4; i++)
#pragma unroll
    for (int j = 0; j < 4; j++) acc[i][j] = (f32x4){0.f, 0.f, 0.f, 0.f};
  int nkt = K >> 6;
  for (int kt = 0; kt < nkt; kt++) {
    __syncthreads();
#pragma unroll
    for (int q = 0; q < 4; q++) {
      int row = q * 32 + wv * 8 + srow;
      size_t ae;
      if (CONV) {
        int rrow = n0 + row;
        ae = (size_t)(rrow + (rrow >> 11) * 4 + (kt >> 4) * 2) * 1024 +
             ((kt & 15) * 64 + kel);
      } else {
        ae = (size_t)(a_off + n0 + row) * K + kt * 64 + kel;
      }
      size_t be = (size_t)(m0 + row) * K + kt * 64 + kel;
      int d = q * 2048 + dst;
      gload_lds(Ah + ae, &sAh[d]);
      if (APAIR) gload_lds(Al + ae, &sAl[d]);
      gload_lds(Bh + be, &sBh[d]);
      gload_lds(Bl + be, &sBl[d]);
    }
    __syncthreads();
#pragma unroll
    for (int kk = 0; kk < 2; kk++) {
      int ko = ((kk * 64 + kb) ^ swz) >> 1;  // elem offset within 64-elem row
      bf16x8 ahf[4], alf[4], bhf[4], blf[4];
#pragma unroll
      for (int i = 0; i < 4; i++) {
        int ra = wr * 64 + i * 16 + lr;
        ahf[i] = *(const bf16x8*)&sAh[ra * 64 + ko];
        if (APAIR) alf[i] = *(const bf16x8*)&sAl[ra * 64 + ko];
        int rb = wc * 64 + i * 16 + lr;
        bhf[i] = *(const bf16x8*)&sBh[rb * 64 + ko];
        blf[i] = *(const bf16x8*)&sBl[rb * 64 + ko];
      }
#pragma unroll
      for (int i = 0; i < 4; i++)
#pragma unroll
        for (int j = 0; j < 4; j++) {
          acc[i][j] = __builtin_amdgcn_mfma_f32_16x16x32_bf16(ahf[i], bhf[j],
                                                              acc[i][j], 0, 0, 0);
          acc[i][j] = __builtin_amdgcn_mfma_f32_16x16x32_bf16(ahf[i], blf[j],
                                                              acc[i][j], 0, 0, 0);
          if (APAIR)
            acc[i][j] = __builtin_amdgcn_mfma_f32_16x16x32_bf16(
                alf[i], bhf[j], acc[i][j], 0, 0, 0);
        }
    }
  }
  // ---- epilogue ----
  float bj[4];
#pragma unroll
  for (int j = 0; j < 4; j++) bj[j] = bias[m0 + wc * 64 + j * 16 + lr];
#pragma unroll
  for (int i = 0; i < 4; i++) {
    int row = n0 + wr * 64 + i * 16 + lg * 4;
#pragma unroll
    for (int rr = 0; rr < 4; rr++) {
      size_t r = (size_t)(c_off + row + rr);
#pragma unroll
      for (int j = 0; j < 4; j++) {
        int col = m0 + wc * 64 + j * 16 + lr;
        float v = acc[i][j][rr] + bj[j];
        size_t idx = r * Nc + col;
        if (EP == 0) {
          Cb[idx] = (__bf16)v;
        } else if (EP == 1) {
          Cf[idx] = v + res[idx];
        } else if (EP == 2) {
          Cb[idx] = (__bf16)gelu_exact(v);
        }
      }
    }
  }
}

// ---------------- fused MoE GEMM: X += sum_e gp[e,row]*(A@We^T + be) --------
// Same tile structure as mgemm; expert-outer loop, dual accumulator:
// per-expert acc folded into tot with gp weighting (incl. bias), single RMW.
__global__ __launch_bounds__(256) void moe_fused(
    const __bf16* __restrict__ Ah, const __bf16* __restrict__ Al,
    const __bf16* __restrict__ EWh, const __bf16* __restrict__ EWl,
    const float* __restrict__ EB, const float* __restrict__ GPT,
    float* __restrict__ X) {
  __shared__ __bf16 sAh[8192];
  __shared__ __bf16 sAl[8192];
  __shared__ __bf16 sBh[8192];
  __shared__ __bf16 sBl[8192];
  int t = threadIdx.x;
  int wv = t >> 6, ln = t & 63;
  int wr = wv >> 1, wc = wv & 1;
  int n0 = blockIdx.x * 128, m0 = blockIdx.y * 128;
  int srow = ln >> 3;
  int kel = ((ln & 7) ^ srow) << 3;
  int dst = wv * 512 + ln * 8;
  int lr = ln & 15, lg = ln >> 4;
  int swz = (ln & 7) << 4;
  int kb = lg << 4;
  f32x4 tot[4][4];
  f32x4 acc[4][4];
#pragma unroll
  for (int i = 0; i < 4; i++)
#pragma unroll
    for (int j = 0; j < 4; j++) {
      tot[i][j] = (f32x4){0.f, 0.f, 0.f, 0.f};
      acc[i][j] = (f32x4){0.f, 0.f, 0.f, 0.f};
    }
  for (int e = 0; e < 8; e++) {
    const __bf16* Bh = EWh + (size_t)e * (CDIM * CDIM);
    const __bf16* Bl = EWl + (size_t)e * (CDIM * CDIM);
    for (int kt = 0; kt < 16; kt++) {
      __syncthreads();
#pragma unroll
      for (int q = 0; q < 4; q++) {
        int row = q * 32 + wv * 8 + srow;
        size_t ae = (size_t)(n0 + row) * CDIM + kt * 64 + kel;
        size_t be = (size_t)(m0 + row) * CDIM + kt * 64 + kel;
        int d = q * 2048 + dst;
        gload_lds(Ah + ae, &sAh[d]);
        gload_lds(Al + ae, &sAl[d]);
        gload_lds(Bh + be, &sBh[d]);
        gload_lds(Bl + be, &sBl[d]);
      }
      __syncthreads();
#pragma unroll
      for (int kk = 0; kk < 2; kk++) {
        int ko = ((kk * 64 + kb) ^ swz) >> 1;
        bf16x8 ahf[4], alf[4], bhf[4], blf[4];
#pragma unroll
        for (int i = 0; i < 4; i++) {
          int ra = wr * 64 + i * 16 + lr;
          ahf[i] = *(const bf16x8*)&sAh[ra * 64 + ko];
          alf[i] = *(const bf16x8*)&sAl[ra * 64 + ko];
          int rb = wc * 64 + i * 16 + lr;
          bhf[i] = *(const bf16x8*)&sBh[rb * 64 + ko];
          blf[i] = *(const bf16x8*)&sBl[rb * 64 + ko];
        }
#pragma unroll
        for (int i = 0; i < 4; i++)
#pragma unroll
          for (int j = 0; j < 4; j++) {
            acc[i][j] = __builtin_amdgcn_mfma_f32_16x16x32_bf16(
                ahf[i], bhf[j], acc[i][j], 0, 0, 0);
            acc[i][j] = __builtin_amdgcn_mfma_f32_16x16x32_bf16(
                ahf[i], blf[j], acc[i][j], 0, 0, 0);
            acc[i][j] = __builtin_amdgcn_mfma_f32_16x16x32_bf16(
                alf[i], bhf[j], acc[i][j], 0, 0, 0);
          }
      }
    }
    // fold expert e into tot: tot += gp_e(row) * (acc + be(col)); reset acc
    float ebj[4];
#pragma unroll
    for (int j = 0; j < 4; j++)
      ebj[j] = EB[(size_t)e * CDIM + m0 + wc * 64 + j * 16 + lr];
#pragma unroll
    for (int i = 0; i < 4; i++) {
      int row = n0 + wr * 64 + i * 16 + lg * 4;
      f32x4 gp4 = *(const f32x4*)&GPT[(size_t)e * NROWS + row];
#pragma unroll
      for (int j = 0; j < 4; j++) {
#pragma unroll
        for (int rr = 0; rr < 4; rr++)
          tot[i][j][rr] += gp4[rr] * (acc[i][j][rr] + ebj[j]);
        acc[i][j] = (f32x4){0.f, 0.f, 0.f, 0.f};
      }
    }
  }
  // ---- single RMW epilogue ----
#pragma unroll
  for (int i = 0; i < 4; i++) {
    int row = n0 + wr * 64 + i * 16 + lg * 4;
#pragma unroll
    for (int rr = 0; rr < 4; rr++) {
      size_t r = (size_t)(row + rr);
#pragma unroll
      for (int j = 0; j < 4; j++) {
        int col = m0 + wc * 64 + j * 16 + lr;
        X[r * CDIM + col] += tot[i][j][rr];
      }
    }
  }
}

// ---------------- conv residual add epilogue is in mgemm EP path -----------
// conv uses dedicated EP: Cf += acc + bias (res add into X) -> reuse EP=1 with
// res==X and Cf==X would double-read; keep a small variant:
template <bool CONV>
__global__ __launch_bounds__(256) void mgemm_accum(
    const __bf16* __restrict__ Ah, const __bf16* __restrict__ Al,
    const __bf16* __restrict__ Bh, const __bf16* __restrict__ Bl,
    const float* __restrict__ bias, float* __restrict__ X, int K) {
  __shared__ __bf16 sAh[8192];
  __shared__ __bf16 sAl[8192];
  __shared__ __bf16 sBh[8192];
  __shared__ __bf16 sBl[8192];
  int t = threadIdx.x;
  int wv = t >> 6, ln = t & 63;
  int wr = wv >> 1, wc = wv & 1;
  int n0 = blockIdx.x * 128, m0 = blockIdx.y * 128;
  int srow = ln >> 3;
  int kel = ((ln & 7) ^ srow) << 3;
  int dst = wv * 512 + ln * 8;
  int lr = ln & 15, lg = ln >> 4;
  int swz = (ln & 7) << 4;
  int kb = lg << 4;
  f32x4 acc[4][4];
#pragma unroll
  for (int i = 0; i < 4; i++)
#pragma unroll
    for (int j = 0; j < 4; j++) acc[i][j] = (f32x4){0.f, 0.f, 0.f, 0.f};
  int nkt = K >> 6;
  for (int kt = 0; kt < nkt; kt++) {
    __syncthreads();
#pragma unroll
    for (int q = 0; q < 4; q++) {
      int row = q * 32 + wv * 8 + srow;
      size_t ae;
      if (CONV) {
        int rrow = n0 + row;
        ae = (size_t)(rrow + (rrow >> 11) * 4 + (kt >> 4) * 2) * 1024 +
             ((kt & 15) * 64 + kel);
      } else {
        ae = (size_t)(n0 + row) * K + kt * 64 + kel;
      }
      size_t be = (size_t)(m0 + row) * K + kt * 64 + kel;
      int d = q * 2048 + dst;
      gload_lds(Ah + ae, &sAh[d]);
      gload_lds(Al + ae, &sAl[d]);
      gload_lds(Bh + be, &sBh[d]);
      gload_lds(Bl + be, &sBl[d]);
    }
    __syncthreads();
#pragma unroll
    for (int kk = 0; kk < 2; kk++) {
      int ko = ((kk * 64 + kb) ^ swz) >> 1;
      bf16x8 ahf[4], alf[4], bhf[4], blf[4];
#pragma unroll
      for (int i = 0; i < 4; i++) {
        int ra = wr * 64 + i * 16 + lr;
        ahf[i] = *(const bf16x8*)&sAh[ra * 64 + ko];
        alf[i] = *(const bf16x8*)&sAl[ra * 64 + ko];
        int rb = wc * 64 + i * 16 + lr;
        bhf[i] = *(const bf16x8*)&sBh[rb * 64 + ko];
        blf[i] = *(const bf16x8*)&sBl[rb * 64 + ko];
      }
#pragma unroll
      for (int i = 0; i < 4; i++)
#pragma unroll
        for (int j = 0; j < 4; j++) {
          acc[i][j] = __builtin_amdgcn_mfma_f32_16x16x32_bf16(ahf[i], bhf[j],
                                                              acc[i][j], 0, 0, 0);
          acc[i][j] = __builtin_amdgcn_mfma_f32_16x16x32_bf16(ahf[i], blf[j],
                                                              acc[i][j], 0, 0, 0);
          acc[i][j] = __builtin_amdgcn_mfma_f32_16x16x32_bf16(alf[i], bhf[j],
                                                              acc[i][j], 0, 0, 0);
        }
    }
  }
  float bj[4];
#pragma unroll
  for (int j = 0; j < 4; j++) bj[j] = bias[m0 + wc * 64 + j * 16 + lr];
#pragma unroll
  for (int i = 0; i < 4; i++) {
    int row = n0 + wr * 64 + i * 16 + lg * 4;
#pragma unroll
    for (int rr = 0; rr < 4; rr++) {
      size_t r = (size_t)(row + rr);
#pragma unroll
      for (int j = 0; j < 4; j++) {
        int col = m0 + wc * 64 + j * 16 + lr;
        X[r * CDIM + col] += acc[i][j][rr] + bj[j];
      }
    }
  }
}

extern "C" void kernel_launch(void* const* d_in, const int* in_sizes, int n_in,
                              void* d_out, int out_size, void* d_ws,
                              size_t ws_size, hipStream_t stream) {
  (void)in_sizes;
  (void)n_in;
  (void)out_size;
  const float* x = (const float*)d_in[0];
  const float* ln1g = (const float*)d_in[1];
  const float* ln1b = (const float*)d_in[2];
  const float* qkvw = (const float*)d_in[3];
  const float* qkvb = (const float*)d_in[4];
  const float* aow = (const float*)d_in[5];
  const float* aob = (const float*)d_in[6];
  const float* ln2g = (const float*)d_in[7];
  const float* ln2b = (const float*)d_in[8];
  const float* convw = (const float*)d_in[9];
  const float* convb = (const float*)d_in[10];
  const float* ln3g = (const float*)d_in[11];
  const float* ln3b = (const float*)d_in[12];
  const float* gatew = (const float*)d_in[13];
  const float* gateb = (const float*)d_in[14];
  const float* expw = (const float*)d_in[15];
  const float* expb = (const float*)d_in[16];
  const float* ff1w = (const float*)d_in[17];
  const float* ff1b = (const float*)d_in[18];
  const float* ff2w = (const float*)d_in[19];
  const float* ff2b = (const float*)d_in[20];
  float* out = (float*)d_out;

  // Workspace (floats): xbuf 8,388,608 | R_W 8,388,608 | R_A1 8,404,992 |
  // R_A2 8,388,608 | gp_t 65,536  => 33,636,352 floats = 134.5 MB
  float* ws = (float*)d_ws;
  float* xbuf = ws;
  __bf16* RW = (__bf16*)(ws + 8388608);
  __bf16* RA1 = (__bf16*)(ws + 16777216);
  __bf16* RA2 = (__bf16*)(ws + 25182208);
  float* gpt = ws + 33570816;
  if (ws_size < 33636352ull * sizeof(float)) return;

  // --- attention branch ---
  split_pair<<<2048, 256, 0, stream>>>(qkvw, RW, RW + 3145728, 786432);
  ln_pair<<<4608, 256, 0, stream>>>(x, RA1, RA1 + 4718592, ln1g, ln1b, ATTROWS,
                                    LDIM, ATTROWS, 0);
  mgemm<0, true, false><<<dim3(36, 24), 256, 0, stream>>>(
      RA1, RA1 + 4718592, RW, RW + 3145728, qkvb, nullptr, nullptr, RA2, 3072,
      1024, 0, 0);
  attn_kernel<<<512, 256, 0, stream>>>(RA2, RA1, RA1 + 8388608);
  split_pair<<<1024, 256, 0, stream>>>(aow, RW, RW + 1048576, 262144);
  mgemm<1, true, false><<<dim3(64, 8), 256, 0, stream>>>(
      RA1, RA1 + 8388608, RW, RW + 1048576, aob, x, xbuf, nullptr, 1024, 1024,
      0, 0);
  // --- dilated conv branch ---
  convw_split<<<12288, 256, 0, stream>>>(convw, RW, RW + 3145728);
  zero_pads<<<64, 256, 0, stream>>>(RA1, RA1 + 8404992);
  ln_pair<<<8192, 256, 0, stream>>>(xbuf, RA1, RA1 + 8404992, ln2g, ln2b, LDIM,
                                    LDIM, 2052, 2);
  mgemm_accum<true><<<dim3(64, 8), 256, 0, stream>>>(
      RA1, RA1 + 8404992, RW, RW + 3145728, convb, xbuf, 3072);
  // --- MoE branch (gate fused into ln3; experts fused into one dispatch) ---
  split_pair<<<2048, 256, 0, stream>>>(expw, RW, RW + 8388608, 2097152);
  ln_pair_gate<<<8192, 256, 0, stream>>>(xbuf, RA1, RA1 + 8388608, ln3g, ln3b,
                                         gatew, gateb, gpt);
  moe_fused<<<dim3(64, 8), 256, 0, stream>>>(RA1, RA1 + 8388608, RW,
                                             RW + 8388608, expb, gpt, xbuf);
  // --- FFN ---
  split_pair<<<2048, 256, 0, stream>>>(ff1w, RW, RW + 4194304, 1048576);
  split_pair<<<2048, 256, 0, stream>>>(ff2w, RW + 8388608, RW + 12582912,
                                       1048576);
  split_pair<<<2048, 256, 0, stream>>>(xbuf, RA1, RA1 + 8388608, 2097152);
  for (int c = 0; c < 2; c++) {
    mgemm<2, true, false><<<dim3(32, 32), 256, 0, stream>>>(
        RA1, RA1 + 8388608, RW, RW + 4194304, ff1b, nullptr, nullptr, RA2,
        4096, 1024, c * 4096, 0);
    mgemm<1, false, false><<<dim3(32, 8), 256, 0, stream>>>(
        RA2, nullptr, RW + 8388608, RW + 12582912, ff2b, xbuf, out, nullptr,
        1024, 4096, 0, c * 4096);
  }
}

// Round 7
// 1190.349 us; speedup vs baseline: 1.2618x; 1.2618x over previous
//
#include <hip/hip_runtime.h>
#include <hip/hip_bf16.h>
#include <math.h>

#define CDIM 1024
#define LDIM 2048
#define NROWS 8192      // B*L
#define ATTROWS 1152    // rows of q/k/v consumed per batch (windows 0..7)

typedef __bf16 bf16x8 __attribute__((ext_vector_type(8)));
typedef __bf16 bf16x4 __attribute__((ext_vector_type(4)));
typedef float f32x4 __attribute__((ext_vector_type(4)));

__device__ __forceinline__ float gelu_exact(float v) {
  return 0.5f * v * (1.0f + erff(v * 0.70710678118654752440f));
}

__device__ __forceinline__ void gload_lds(const __bf16* g, __bf16* l) {
  __builtin_amdgcn_global_load_lds(
      (const __attribute__((address_space(1))) void*)(const void*)g,
      (__attribute__((address_space(3))) void*)(void*)l, 16, 0, 0);
}

// ---------------- fp32 -> (hi,lo) bf16 split, vectorized (activations) -----
__global__ __launch_bounds__(256) void split_pair(const float* __restrict__ src,
                                                  __bf16* __restrict__ hi,
                                                  __bf16* __restrict__ lo,
                                                  int n4) {
  int idx = blockIdx.x * 256 + threadIdx.x;
  int stride = gridDim.x * 256;
  for (int i = idx; i < n4; i += stride) {
    float4 v = ((const float4*)src)[i];
    bf16x4 h, l;
    h[0] = (__bf16)v.x; l[0] = (__bf16)(v.x - (float)h[0]);
    h[1] = (__bf16)v.y; l[1] = (__bf16)(v.y - (float)h[1]);
    h[2] = (__bf16)v.z; l[2] = (__bf16)(v.z - (float)h[2]);
    h[3] = (__bf16)v.w; l[3] = (__bf16)(v.w - (float)h[3]);
    ((bf16x4*)hi)[i] = h;
    ((bf16x4*)lo)[i] = l;
  }
}

// ---------------- fp32 -> bf16 single plane (weights) ----------------------
__global__ __launch_bounds__(256) void to_bf16(const float* __restrict__ src,
                                               __bf16* __restrict__ dst,
                                               int n4) {
  int idx = blockIdx.x * 256 + threadIdx.x;
  int stride = gridDim.x * 256;
  for (int i = idx; i < n4; i += stride) {
    float4 v = ((const float4*)src)[i];
    bf16x4 h;
    h[0] = (__bf16)v.x;
    h[1] = (__bf16)v.y;
    h[2] = (__bf16)v.z;
    h[3] = (__bf16)v.w;
    ((bf16x4*)dst)[i] = h;
  }
}

// ---------------- conv weight transpose: w2[o][k*1024+i] = cw[o][i][k] ------
__global__ __launch_bounds__(256) void convw_bf16(const float* __restrict__ cw,
                                                  __bf16* __restrict__ wh) {
  int idx = blockIdx.x * 256 + threadIdx.x;  // < 1024*3072
  int o = idx / 3072;
  int r = idx - o * 3072;
  int k = r >> 10;
  int i = r & 1023;
  wh[idx] = (__bf16)cw[(size_t)(o * 1024 + i) * 3 + k];
}

// ---------------- zero pads of the ln2 padded buffer (rows 0,1,2050,2051) ---
__global__ __launch_bounds__(256) void zero_pads(__bf16* __restrict__ ph,
                                                 __bf16* __restrict__ pl) {
  int i = blockIdx.x * 256 + threadIdx.x;  // < 16384
  if (i >= 16384) return;
  int b = i >> 12;
  int r4 = (i >> 10) & 3;
  int c = i & 1023;
  int row = b * 2052 + (r4 < 2 ? r4 : 2048 + r4);
  ph[(size_t)row * 1024 + c] = (__bf16)0.f;
  pl[(size_t)row * 1024 + c] = (__bf16)0.f;
}

// ---------------- LayerNorm -> (hi,lo) bf16 pair planes ----------------
__global__ __launch_bounds__(256) void ln_pair(
    const float* __restrict__ src, __bf16* __restrict__ dh,
    __bf16* __restrict__ dl, const float* __restrict__ g,
    const float* __restrict__ b, int rows_pb, int src_bstride, int dst_bstride,
    int dst_pad) {
  int r = blockIdx.x;
  int bb = r / rows_pb, l = r - bb * rows_pb;
  const float4* row =
      (const float4*)(src + (size_t)(bb * src_bstride + l) * CDIM);
  size_t drow = (size_t)(bb * dst_bstride + dst_pad + l) * CDIM;
  int t = threadIdx.x;
  float4 v = row[t];
  float s = v.x + v.y + v.z + v.w;
  float sq = v.x * v.x + v.y * v.y + v.z * v.z + v.w * v.w;
#pragma unroll
  for (int off = 32; off > 0; off >>= 1) {
    s += __shfl_down(s, off);
    sq += __shfl_down(sq, off);
  }
  __shared__ float red[8];
  int wave = t >> 6;
  if ((t & 63) == 0) {
    red[wave] = s;
    red[4 + wave] = sq;
  }
  __syncthreads();
  if (t == 0) {
    float st = red[0] + red[1] + red[2] + red[3];
    float sqt = red[4] + red[5] + red[6] + red[7];
    float m = st * (1.0f / CDIM);
    float var = sqt * (1.0f / CDIM) - m * m;
    red[0] = m;
    red[1] = rsqrtf(var + 1e-5f);
  }
  __syncthreads();
  float m = red[0], rs = red[1];
  float4 gv = ((const float4*)g)[t];
  float4 bv = ((const float4*)b)[t];
  float o0 = (v.x - m) * rs * gv.x + bv.x;
  float o1 = (v.y - m) * rs * gv.y + bv.y;
  float o2 = (v.z - m) * rs * gv.z + bv.z;
  float o3 = (v.w - m) * rs * gv.w + bv.w;
  bf16x4 h, lo4;
  h[0] = (__bf16)o0; lo4[0] = (__bf16)(o0 - (float)h[0]);
  h[1] = (__bf16)o1; lo4[1] = (__bf16)(o1 - (float)h[1]);
  h[2] = (__bf16)o2; lo4[2] = (__bf16)(o2 - (float)h[2]);
  h[3] = (__bf16)o3; lo4[3] = (__bf16)(o3 - (float)h[3]);
  *(bf16x4*)&dh[drow + t * 4] = h;
  *(bf16x4*)&dl[drow + t * 4] = lo4;
}

// ---------------- LayerNorm + fused MoE gate (ln3): also emits gp_t[8][N] --
__global__ __launch_bounds__(256) void ln_pair_gate(
    const float* __restrict__ src, __bf16* __restrict__ dh,
    __bf16* __restrict__ dl, const float* __restrict__ g,
    const float* __restrict__ b, const float* __restrict__ gw,
    const float* __restrict__ gb, float* __restrict__ gpt) {
  int r = blockIdx.x;
  const float4* row = (const float4*)(src + (size_t)r * CDIM);
  size_t drow = (size_t)r * CDIM;
  int t = threadIdx.x;
  float4 v = row[t];
  float s = v.x + v.y + v.z + v.w;
  float sq = v.x * v.x + v.y * v.y + v.z * v.z + v.w * v.w;
#pragma unroll
  for (int off = 32; off > 0; off >>= 1) {
    s += __shfl_down(s, off);
    sq += __shfl_down(sq, off);
  }
  __shared__ float red[8];
  __shared__ float gred[4][8];
  int wave = t >> 6;
  if ((t & 63) == 0) {
    red[wave] = s;
    red[4 + wave] = sq;
  }
  __syncthreads();
  if (t == 0) {
    float st = red[0] + red[1] + red[2] + red[3];
    float sqt = red[4] + red[5] + red[6] + red[7];
    float m = st * (1.0f / CDIM);
    float var = sqt * (1.0f / CDIM) - m * m;
    red[0] = m;
    red[1] = rsqrtf(var + 1e-5f);
  }
  __syncthreads();
  float m = red[0], rs = red[1];
  float4 gv = ((const float4*)g)[t];
  float4 bv = ((const float4*)b)[t];
  float o0 = (v.x - m) * rs * gv.x + bv.x;
  float o1 = (v.y - m) * rs * gv.y + bv.y;
  float o2 = (v.z - m) * rs * gv.z + bv.z;
  float o3 = (v.w - m) * rs * gv.w + bv.w;
  bf16x4 h, lo4;
  h[0] = (__bf16)o0; lo4[0] = (__bf16)(o0 - (float)h[0]);
  h[1] = (__bf16)o1; lo4[1] = (__bf16)(o1 - (float)h[1]);
  h[2] = (__bf16)o2; lo4[2] = (__bf16)(o2 - (float)h[2]);
  h[3] = (__bf16)o3; lo4[3] = (__bf16)(o3 - (float)h[3]);
  *(bf16x4*)&dh[drow + t * 4] = h;
  *(bf16x4*)&dl[drow + t * 4] = lo4;
  // gate partial dots on the fp32 LN output held in registers
  float gp8[8];
#pragma unroll
  for (int e = 0; e < 8; e++) {
    float4 w = ((const float4*)gw)[e * 256 + t];
    gp8[e] = o0 * w.x + o1 * w.y + o2 * w.z + o3 * w.w;
  }
#pragma unroll
  for (int off = 32; off > 0; off >>= 1)
#pragma unroll
    for (int e = 0; e < 8; e++) gp8[e] += __shfl_down(gp8[e], off);
  if ((t & 63) == 0)
#pragma unroll
    for (int e = 0; e < 8; e++) gred[wave][e] = gp8[e];
  __syncthreads();
  if (t == 0) {
    float lg[8];
#pragma unroll
    for (int e = 0; e < 8; e++)
      lg[e] = gred[0][e] + gred[1][e] + gred[2][e] + gred[3][e] + gb[e];
    float mx = lg[0];
#pragma unroll
    for (int e = 1; e < 8; e++) mx = fmaxf(mx, lg[e]);
    float ex[8];
    float sum = 0.f;
#pragma unroll
    for (int e = 0; e < 8; e++) {
      ex[e] = expf(lg[e] - mx);
      sum += ex[e];
    }
    float inv = 1.0f / sum;
#pragma unroll
    for (int e = 0; e < 8; e++) gpt[(size_t)e * NROWS + r] = ex[e] * inv;
  }
}

// ---------------- fused local attention (unfold-faithful), bf16 in/out ------
__global__ __launch_bounds__(256) void attn_kernel(const __bf16* __restrict__ QKV,
                                                   __bf16* __restrict__ Oh,
                                                   __bf16* __restrict__ Ol) {
  __shared__ float Qc[64][68];
  __shared__ float Kc[64][68];
  __shared__ float At[64][65];
  int blk = blockIdx.x;
  int n = blk & 7, hd_ = (blk >> 3) & 15, b = blk >> 7;
  int t = threadIdx.x;
  int dt = t >> 4, et = t & 15;
  int lw = t >> 4, lf = (t & 15) * 4;
  const __bf16* base = QKV + (size_t)(b * ATTROWS + n * 128) * 3072 + hd_ * 64;
  float acc[4][4] = {};
  for (int wcc = 0; wcc < 4; wcc++) {
    __syncthreads();
#pragma unroll
    for (int p = 0; p < 4; p++) {
      int w = p * 16 + lw;
      const __bf16* rp = base + (size_t)(wcc * 64 + w) * 3072 + lf;
      bf16x4 qv = *(const bf16x4*)rp;
      bf16x4 kv = *(const bf16x4*)(rp + 1024);
      Qc[w][lf + 0] = (float)qv[0]; Qc[w][lf + 1] = (float)qv[1];
      Qc[w][lf + 2] = (float)qv[2]; Qc[w][lf + 3] = (float)qv[3];
      Kc[w][lf + 0] = (float)kv[0]; Kc[w][lf + 1] = (float)kv[1];
      Kc[w][lf + 2] = (float)kv[2]; Kc[w][lf + 3] = (float)kv[3];
    }
    __syncthreads();
#pragma unroll 8
    for (int k = 0; k < 64; k++) {
      float4 qa = *(const float4*)&Qc[k][dt * 4];
      float4 kb = *(const float4*)&Kc[k][et * 4];
      float a4[4] = {qa.x, qa.y, qa.z, qa.w};
      float b4[4] = {kb.x, kb.y, kb.z, kb.w};
#pragma unroll
      for (int i = 0; i < 4; i++)
#pragma unroll
        for (int j = 0; j < 4; j++) acc[i][j] = fmaf(a4[i], b4[j], acc[i][j]);
    }
  }
  __syncthreads();
#pragma unroll
  for (int i = 0; i < 4; i++)
#pragma unroll
    for (int j = 0; j < 4; j++) At[dt * 4 + i][et * 4 + j] = acc[i][j] * 0.125f;
  __syncthreads();
  if (t < 64) {  // softmax over e per row d=t
    float mx = -1e30f;
    for (int e = 0; e < 64; e++) mx = fmaxf(mx, At[t][e]);
    float s = 0.f;
    for (int e = 0; e < 64; e++) {
      float ex = expf(At[t][e] - mx);
      At[t][e] = ex;
      s += ex;
    }
    float inv = 1.0f / s;
    for (int e = 0; e < 64; e++) At[t][e] *= inv;
  }
  __syncthreads();
  float* Vc = &Qc[0][0];  // reuse Qc as Vc[e][j], stride 68
  for (int wb = 0; wb < 4; wb++) {
    __syncthreads();
#pragma unroll
    for (int p = 0; p < 4; p++) {
      int j = p * 16 + lw;
      const __bf16* rp = base + (size_t)(wb * 64 + j) * 3072 + 2048 + lf;
      bf16x4 vv = *(const bf16x4*)rp;
      Vc[(lf + 0) * 68 + j] = (float)vv[0];
      Vc[(lf + 1) * 68 + j] = (float)vv[1];
      Vc[(lf + 2) * 68 + j] = (float)vv[2];
      Vc[(lf + 3) * 68 + j] = (float)vv[3];
    }
    __syncthreads();
    float o[4][4] = {};
    for (int e = 0; e < 64; e++) {
      float a4[4] = {At[dt * 4 + 0][e], At[dt * 4 + 1][e], At[dt * 4 + 2][e],
                     At[dt * 4 + 3][e]};
      float4 vv = *(const float4*)&Vc[e * 68 + et * 4];
      float b4[4] = {vv.x, vv.y, vv.z, vv.w};
#pragma unroll
      for (int i = 0; i < 4; i++)
#pragma unroll
        for (int j = 0; j < 4; j++) o[i][j] = fmaf(a4[i], b4[j], o[i][j]);
    }
#pragma unroll
    for (int i = 0; i < 4; i++) {
      int d = dt * 4 + i;
      int tok = n * 256 + d * 4 + wb;
      size_t ob = (size_t)(b * LDIM + tok) * CDIM + hd_ * 64 + et * 4;
      bf16x4 oh, ol;
#pragma unroll
      for (int jj = 0; jj < 4; jj++) {
        float v = o[i][jj];
        __bf16 hh = (__bf16)v;
        oh[jj] = hh;
        ol[jj] = (__bf16)(v - (float)hh);
      }
      *(bf16x4*)&Oh[ob] = oh;
      *(bf16x4*)&Ol[ob] = ol;
    }
  }
}

// ---------------- 2-term split MFMA GEMM: C = (Ah+Al)@Bh^T (+epilogues) ----
// 128x128 tile, BK=64, 4 waves (2x2), 4x4 frags of 16x16x32 per wave.
// A split hi/lo (APAIR) or single; B single bf16 plane (weights).
// EP: 0 = bf16 out (bias), 1 = fp32 out = acc+bias+res, 2 = bf16 gelu out.
template <int EP, bool APAIR, bool CONV>
__global__ __launch_bounds__(256) void mgemm(
    const __bf16* __restrict__ Ah, const __bf16* __restrict__ Al,
    const __bf16* __restrict__ Bh, const float* __restrict__ bias,
    const float* __restrict__ res, float* __restrict__ Cf,
    __bf16* __restrict__ Cb, int Nc, int K, int a_off, int c_off) {
  __shared__ __bf16 sAh[8192];
  __shared__ __bf16 sAl[APAIR ? 8192 : 16];
  __shared__ __bf16 sBh[8192];
  int t = threadIdx.x;
  int wv = t >> 6, ln = t & 63;
  int wr = wv >> 1, wc = wv & 1;
  int n0 = blockIdx.x * 128, m0 = blockIdx.y * 128;
  int srow = ln >> 3;
  int kel = ((ln & 7) ^ srow) << 3;      // swizzled source k-elem offset
  int dst = wv * 512 + ln * 8;           // LDS elems (per q: +q*2048)
  int lr = ln & 15, lg = ln >> 4;
  int swz = (ln & 7) << 4;
  int kb = lg << 4;
  f32x4 acc[4][4];
#pragma unroll
  for (int i = 0; i < 4; i++)
#pragma unroll
    for (int j = 0; j < 4; j++) acc[i][j] = (f32x4){0.f, 0.f, 0.f, 0.f};
  int nkt = K >> 6;
  for (int kt = 0; kt < nkt; kt++) {
    __syncthreads();
#pragma unroll
    for (int q = 0; q < 4; q++) {
      int row = q * 32 + wv * 8 + srow;
      size_t ae;
      if (CONV) {
        int rrow = n0 + row;
        ae = (size_t)(rrow + (rrow >> 11) * 4 + (kt >> 4) * 2) * 1024 +
             ((kt & 15) * 64 + kel);
      } else {
        ae = (size_t)(a_off + n0 + row) * K + kt * 64 + kel;
      }
      size_t be = (size_t)(m0 + row) * K + kt * 64 + kel;
      int d = q * 2048 + dst;
      gload_lds(Ah + ae, &sAh[d]);
      if (APAIR) gload_lds(Al + ae, &sAl[d]);
      gload_lds(Bh + be, &sBh[d]);
    }
    __syncthreads();
#pragma unroll
    for (int kk = 0; kk < 2; kk++) {
      int ko = ((kk * 64 + kb) ^ swz) >> 1;  // byte sel -> elem offset
      bf16x8 ahf[4], alf[4], bhf[4];
#pragma unroll
      for (int i = 0; i < 4; i++) {
        int ra = wr * 64 + i * 16 + lr;
        ahf[i] = *(const bf16x8*)&sAh[ra * 64 + ko];
        if (APAIR) alf[i] = *(const bf16x8*)&sAl[ra * 64 + ko];
        int rb = wc * 64 + i * 16 + lr;
        bhf[i] = *(const bf16x8*)&sBh[rb * 64 + ko];
      }
#pragma unroll
      for (int i = 0; i < 4; i++)
#pragma unroll
        for (int j = 0; j < 4; j++) {
          acc[i][j] = __builtin_amdgcn_mfma_f32_16x16x32_bf16(ahf[i], bhf[j],
                                                              acc[i][j], 0, 0, 0);
          if (APAIR)
            acc[i][j] = __builtin_amdgcn_mfma_f32_16x16x32_bf16(
                alf[i], bhf[j], acc[i][j], 0, 0, 0);
        }
    }
  }
  // ---- epilogue ----
  float bj[4];
#pragma unroll
  for (int j = 0; j < 4; j++) bj[j] = bias[m0 + wc * 64 + j * 16 + lr];
#pragma unroll
  for (int i = 0; i < 4; i++) {
    int row = n0 + wr * 64 + i * 16 + lg * 4;
#pragma unroll
    for (int rr = 0; rr < 4; rr++) {
      size_t r = (size_t)(c_off + row + rr);
#pragma unroll
      for (int j = 0; j < 4; j++) {
        int col = m0 + wc * 64 + j * 16 + lr;
        float v = acc[i][j][rr] + bj[j];
        size_t idx = r * Nc + col;
        if (EP == 0) {
          Cb[idx] = (__bf16)v;
        } else if (EP == 1) {
          Cf[idx] = v + res[idx];
        } else if (EP == 2) {
          Cb[idx] = (__bf16)gelu_exact(v);
        }
      }
    }
  }
}

// ---------------- accumulate variant: X += A@Bh^T + bias (conv) ------------
template <bool CONV>
__global__ __launch_bounds__(256) void mgemm_accum(
    const __bf16* __restrict__ Ah, const __bf16* __restrict__ Al,
    const __bf16* __restrict__ Bh, const float* __restrict__ bias,
    float* __restrict__ X, int K) {
  __shared__ __bf16 sAh[8192];
  __shared__ __bf16 sAl[8192];
  __shared__ __bf16 sBh[8192];
  int t = threadIdx.x;
  int wv = t >> 6, ln = t & 63;
  int wr = wv >> 1, wc = wv & 1;
  int n0 = blockIdx.x * 128, m0 = blockIdx.y * 128;
  int srow = ln >> 3;
  int kel = ((ln & 7) ^ srow) << 3;
  int dst = wv * 512 + ln * 8;
  int lr = ln & 15, lg = ln >> 4;
  int swz = (ln & 7) << 4;
  int kb = lg << 4;
  f32x4 acc[4][4];
#pragma unroll
  for (int i = 0; i < 4; i++)
#pragma unroll
    for (int j = 0; j < 4; j++) acc[i][j] = (f32x4){0.f, 0.f, 0.f, 0.f};
  int nkt = K >> 6;
  for (int kt = 0; kt < nkt; kt++) {
    __syncthreads();
#pragma unroll
    for (int q = 0; q < 4; q++) {
      int row = q * 32 + wv * 8 + srow;
      size_t ae;
      if (CONV) {
        int rrow = n0 + row;
        ae = (size_t)(rrow + (rrow >> 11) * 4 + (kt >> 4) * 2) * 1024 +
             ((kt & 15) * 64 + kel);
      } else {
        ae = (size_t)(n0 + row) * K + kt * 64 + kel;
      }
      size_t be = (size_t)(m0 + row) * K + kt * 64 + kel;
      int d = q * 2048 + dst;
      gload_lds(Ah + ae, &sAh[d]);
      gload_lds(Al + ae, &sAl[d]);
      gload_lds(Bh + be, &sBh[d]);
    }
    __syncthreads();
#pragma unroll
    for (int kk = 0; kk < 2; kk++) {
      int ko = ((kk * 64 + kb) ^ swz) >> 1;
      bf16x8 ahf[4], alf[4], bhf[4];
#pragma unroll
      for (int i = 0; i < 4; i++) {
        int ra = wr * 64 + i * 16 + lr;
        ahf[i] = *(const bf16x8*)&sAh[ra * 64 + ko];
        alf[i] = *(const bf16x8*)&sAl[ra * 64 + ko];
        int rb = wc * 64 + i * 16 + lr;
        bhf[i] = *(const bf16x8*)&sBh[rb * 64 + ko];
      }
#pragma unroll
      for (int i = 0; i < 4; i++)
#pragma unroll
        for (int j = 0; j < 4; j++) {
          acc[i][j] = __builtin_amdgcn_mfma_f32_16x16x32_bf16(ahf[i], bhf[j],
                                                              acc[i][j], 0, 0, 0);
          acc[i][j] = __builtin_amdgcn_mfma_f32_16x16x32_bf16(alf[i], bhf[j],
                                                              acc[i][j], 0, 0, 0);
        }
    }
  }
  float bj[4];
#pragma unroll
  for (int j = 0; j < 4; j++) bj[j] = bias[m0 + wc * 64 + j * 16 + lr];
#pragma unroll
  for (int i = 0; i < 4; i++) {
    int row = n0 + wr * 64 + i * 16 + lg * 4;
#pragma unroll
    for (int rr = 0; rr < 4; rr++) {
      size_t r = (size_t)(row + rr);
#pragma unroll
      for (int j = 0; j < 4; j++) {
        int col = m0 + wc * 64 + j * 16 + lr;
        X[r * CDIM + col] += acc[i][j][rr] + bj[j];
      }
    }
  }
}

// ---------------- fused MoE GEMM: X += sum_e gp[e,row]*(A@We^T + be) --------
__global__ __launch_bounds__(256) void moe_fused(
    const __bf16* __restrict__ Ah, const __bf16* __restrict__ Al,
    const __bf16* __restrict__ EWh, const float* __restrict__ EB,
    const float* __restrict__ GPT, float* __restrict__ X) {
  __shared__ __bf16 sAh[8192];
  __shared__ __bf16 sAl[8192];
  __shared__ __bf16 sBh[8192];
  int t = threadIdx.x;
  int wv = t >> 6, ln = t & 63;
  int wr = wv >> 1, wc = wv & 1;
  int n0 = blockIdx.x * 128, m0 = blockIdx.y * 128;
  int srow = ln >> 3;
  int kel = ((ln & 7) ^ srow) << 3;
  int dst = wv * 512 + ln * 8;
  int lr = ln & 15, lg = ln >> 4;
  int swz = (ln & 7) << 4;
  int kb = lg << 4;
  f32x4 tot[4][4];
  f32x4 acc[4][4];
#pragma unroll
  for (int i = 0; i < 4; i++)
#pragma unroll
    for (int j = 0; j < 4; j++) {
      tot[i][j] = (f32x4){0.f, 0.f, 0.f, 0.f};
      acc[i][j] = (f32x4){0.f, 0.f, 0.f, 0.f};
    }
  for (int e = 0; e < 8; e++) {
    const __bf16* Bh = EWh + (size_t)e * (CDIM * CDIM);
    for (int kt = 0; kt < 16; kt++) {
      __syncthreads();
#pragma unroll
      for (int q = 0; q < 4; q++) {
        int row = q * 32 + wv * 8 + srow;
        size_t ae = (size_t)(n0 + row) * CDIM + kt * 64 + kel;
        size_t be = (size_t)(m0 + row) * CDIM + kt * 64 + kel;
        int d = q * 2048 + dst;
        gload_lds(Ah + ae, &sAh[d]);
        gload_lds(Al + ae, &sAl[d]);
        gload_lds(Bh + be, &sBh[d]);
      }
      __syncthreads();
#pragma unroll
      for (int kk = 0; kk < 2; kk++) {
        int ko = ((kk * 64 + kb) ^ swz) >> 1;
        bf16x8 ahf[4], alf[4], bhf[4];
#pragma unroll
        for (int i = 0; i < 4; i++) {
          int ra = wr * 64 + i * 16 + lr;
          ahf[i] = *(const bf16x8*)&sAh[ra * 64 + ko];
          alf[i] = *(const bf16x8*)&sAl[ra * 64 + ko];
          int rb = wc * 64 + i * 16 + lr;
          bhf[i] = *(const bf16x8*)&sBh[rb * 64 + ko];
        }
#pragma unroll
        for (int i = 0; i < 4; i++)
#pragma unroll
          for (int j = 0; j < 4; j++) {
            acc[i][j] = __builtin_amdgcn_mfma_f32_16x16x32_bf16(
                ahf[i], bhf[j], acc[i][j], 0, 0, 0);
            acc[i][j] = __builtin_amdgcn_mfma_f32_16x16x32_bf16(
                alf[i], bhf[j], acc[i][j], 0, 0, 0);
          }
      }
    }
    // fold expert e: tot += gp_e(row) * (acc + be(col)); reset acc
    float ebj[4];
#pragma unroll
    for (int j = 0; j < 4; j++)
      ebj[j] = EB[(size_t)e * CDIM + m0 + wc * 64 + j * 16 + lr];
#pragma unroll
    for (int i = 0; i < 4; i++) {
      int row = n0 + wr * 64 + i * 16 + lg * 4;
      f32x4 gp4 = *(const f32x4*)&GPT[(size_t)e * NROWS + row];
#pragma unroll
      for (int j = 0; j < 4; j++) {
#pragma unroll
        for (int rr = 0; rr < 4; rr++)
          tot[i][j][rr] += gp4[rr] * (acc[i][j][rr] + ebj[j]);
        acc[i][j] = (f32x4){0.f, 0.f, 0.f, 0.f};
      }
    }
  }
  // ---- single RMW epilogue ----
#pragma unroll
  for (int i = 0; i < 4; i++) {
    int row = n0 + wr * 64 + i * 16 + lg * 4;
#pragma unroll
    for (int rr = 0; rr < 4; rr++) {
      size_t r = (size_t)(row + rr);
#pragma unroll
      for (int j = 0; j < 4; j++) {
        int col = m0 + wc * 64 + j * 16 + lr;
        X[r * CDIM + col] += tot[i][j][rr];
      }
    }
  }
}

extern "C" void kernel_launch(void* const* d_in, const int* in_sizes, int n_in,
                              void* d_out, int out_size, void* d_ws,
                              size_t ws_size, hipStream_t stream) {
  (void)in_sizes;
  (void)n_in;
  (void)out_size;
  const float* x = (const float*)d_in[0];
  const float* ln1g = (const float*)d_in[1];
  const float* ln1b = (const float*)d_in[2];
  const float* qkvw = (const float*)d_in[3];
  const float* qkvb = (const float*)d_in[4];
  const float* aow = (const float*)d_in[5];
  const float* aob = (const float*)d_in[6];
  const float* ln2g = (const float*)d_in[7];
  const float* ln2b = (const float*)d_in[8];
  const float* convw = (const float*)d_in[9];
  const float* convb = (const float*)d_in[10];
  const float* ln3g = (const float*)d_in[11];
  const float* ln3b = (const float*)d_in[12];
  const float* gatew = (const float*)d_in[13];
  const float* gateb = (const float*)d_in[14];
  const float* expw = (const float*)d_in[15];
  const float* expb = (const float*)d_in[16];
  const float* ff1w = (const float*)d_in[17];
  const float* ff1b = (const float*)d_in[18];
  const float* ff2w = (const float*)d_in[19];
  const float* ff2b = (const float*)d_in[20];
  float* out = (float*)d_out;

  // Workspace (floats): xbuf 8,388,608 | RW 4,194,304 (8.4M bf16, weights) |
  // RA1 8,404,992 (16.8M bf16 act pairs) | RA2 8,388,608 (16.8M bf16) |
  // gpt 65,536  => 29,442,048 floats = 117.8 MB
  float* ws = (float*)d_ws;
  float* xbuf = ws;
  __bf16* RW = (__bf16*)(ws + 8388608);
  __bf16* RA1 = (__bf16*)(ws + 12582912);
  __bf16* RA2 = (__bf16*)(ws + 20987904);
  float* gpt = ws + 29376512;
  if (ws_size < 29442048ull * sizeof(float)) return;

  // --- attention branch ---
  to_bf16<<<2048, 256, 0, stream>>>(qkvw, RW, 786432);
  ln_pair<<<4608, 256, 0, stream>>>(x, RA1, RA1 + 4718592, ln1g, ln1b, ATTROWS,
                                    LDIM, ATTROWS, 0);
  mgemm<0, true, false><<<dim3(36, 24), 256, 0, stream>>>(
      RA1, RA1 + 4718592, RW, qkvb, nullptr, nullptr, RA2, 3072, 1024, 0, 0);
  attn_kernel<<<512, 256, 0, stream>>>(RA2, RA1, RA1 + 8388608);
  to_bf16<<<1024, 256, 0, stream>>>(aow, RW + 3145728, 262144);
  mgemm<1, true, false><<<dim3(64, 8), 256, 0, stream>>>(
      RA1, RA1 + 8388608, RW + 3145728, aob, x, xbuf, nullptr, 1024, 1024, 0,
      0);
  // --- dilated conv branch ---
  convw_bf16<<<12288, 256, 0, stream>>>(convw, RW);
  zero_pads<<<64, 256, 0, stream>>>(RA1, RA1 + 8404992);
  ln_pair<<<8192, 256, 0, stream>>>(xbuf, RA1, RA1 + 8404992, ln2g, ln2b, LDIM,
                                    LDIM, 2052, 2);
  mgemm_accum<true><<<dim3(64, 8), 256, 0, stream>>>(RA1, RA1 + 8404992, RW,
                                                     convb, xbuf, 3072);
  // --- MoE branch (gate fused into ln3; experts fused into one dispatch) ---
  to_bf16<<<2048, 256, 0, stream>>>(expw, RW, 2097152);
  ln_pair_gate<<<8192, 256, 0, stream>>>(xbuf, RA1, RA1 + 8388608, ln3g, ln3b,
                                         gatew, gateb, gpt);
  moe_fused<<<dim3(64, 8), 256, 0, stream>>>(RA1, RA1 + 8388608, RW, expb, gpt,
                                             xbuf);
  // --- FFN ---
  to_bf16<<<2048, 256, 0, stream>>>(ff1w, RW, 1048576);
  to_bf16<<<2048, 256, 0, stream>>>(ff2w, RW + 4194304, 1048576);
  split_pair<<<2048, 256, 0, stream>>>(xbuf, RA1, RA1 + 8388608, 2097152);
  for (int c = 0; c < 2; c++) {
    mgemm<2, true, false><<<dim3(32, 32), 256, 0, stream>>>(
        RA1, RA1 + 8388608, RW, ff1b, nullptr, nullptr, RA2, 4096, 1024,
        c * 4096, 0);
    mgemm<1, false, false><<<dim3(32, 8), 256, 0, stream>>>(
        RA2, nullptr, RW + 4194304, ff2b, xbuf, out, nullptr, 1024, 4096, 0,
        c * 4096);
  }
}